// Round 9
// baseline (136.346 us; speedup 1.0000x reference)
//
#include <hip/hip_runtime.h>
#include <hip/hip_bf16.h>

// 1-NN VQ via split-bf16 MFMA + exact fp32 refinement.
//   score[q][k] = csq[k] - 2*dot(q,c_k); out = argmin_k (lowest-k tie-break).
// Phase 0 (knn_prep): codebook -> bf16 hi/lo fragment-ready cbB (kb-major) + csq.
// Phase A (knn_mfma): persistent codebook, wave-pair n-split (r18).
//   r17 result: spill-free TLP=2 got mfma to ~39 us (out of rocprof top-5;
//   total 121.9). Remaining cost model: at m=1 every wave reads the FULL
//   128 KB codebook per batch -> 4 MB/CU ds_read_b128 ~= 16-20 us hard LDS
//   floor at 85-112 B/cyc/CU. Only way down: more q per B-read (m=2), which
//   at t=16 means 128 AGPR -> the r15 spill.
//   r18: m=2 AND t=8 -- wave pairs {2p, 2p+1} split the 16 n-tiles in half.
//   acc[2][8]=64 AGPR + ah/al[2][4]=64 VGPR -> live ~175 << 256, spill-safe
//   at 2 waves/SIMD. Per-q B traffic halves (8->4 KB/q): 2 MB/CU, floor
//   ~8-10 us. Cost: per-batch cross-pair top-2 merge via 6 KB double-buffered
//   LDS scratch + ONE __syncthreads per batch (waves work-symmetric).
//   Merge-owner waves one-per-SIMD (0,2,5,7). Top-2-of-union: B=min(b0,b1),
//   S = b0<b1 ? min(s0,b1) : min(s1,b0); ties -> gap 0 < T -> refine's exact
//   lowest-k pass, so approx pass needs no tie-break.
//   Structure: whole split codebook in LDS once (16x gload_lds w=16/wave,
//   linear dest); 4 batches x (4 pairs x 32 q); K-loop pure ds_read_b128 +
//   MFMA; dot ~= qh.ch+ql.ch+qh.cl (err ~1.9e-3); merged top-2 gap <
//   T=0.004 -> worklist.
// Phase B (knn_refine): exact fp32 rescan (u64 keys, lowest-k tie-break).

typedef __bf16 bf16x8 __attribute__((ext_vector_type(8)));
typedef float  floatx4 __attribute__((ext_vector_type(4)));

#define MFMA16 __builtin_amdgcn_mfma_f32_16x16x32_bf16

#define CNT_OFF 0
#define CSQ_OFF 1024
#define CBB_OFF 4096
#define WL_OFF  (4096 + 131072)
#define WL_CAP  32768
#define T_FLAG  0.004f

typedef __attribute__((address_space(1))) const unsigned int gu32;
typedef __attribute__((address_space(3))) unsigned int lu32;

__device__ __forceinline__ unsigned fmap(float f) {
    unsigned u = __float_as_uint(f);
    return (u & 0x80000000u) ? ~u : (u | 0x80000000u);
}

// ---------------- Phase 0: codebook split, kb-major fragment layout, csq ----------------
// cbB element index = ((kb*16 + t)*2 + part)*512 + ln*8 + j   (= id*8 below)
//   kb = k-chunk 0..3; t = ntile 0..15; part: 0=hi 1=lo;
//   lane ln: n = t*16 + (ln&15), k = kb*32 + (ln>>4)*8 + j.
__global__ void knn_prep(const float* __restrict__ cb, __bf16* __restrict__ cbB,
                         float* __restrict__ csq, int* __restrict__ cnt) {
    const int tid = threadIdx.x;
    const int id = blockIdx.x * 256 + tid;       // 0..8191
    if (id == 0) *cnt = 0;
    const int ln = id & 63;
    const int part = (id >> 6) & 1;
    const int step = id >> 7;                    // kb*16 + t
    const int t4 = step & 15;
    const int kb = step >> 4;
    const int n = t4 * 16 + (ln & 15);
    const int k0 = kb * 32 + (ln >> 4) * 8;
    const float* src = cb + (size_t)n * 128 + k0;
    union { __bf16 h[8]; uint4 u; } p;
#pragma unroll
    for (int j = 0; j < 8; ++j) {
        float f = src[j];
        __bf16 hh = (__bf16)f;
        p.h[j] = (part == 0) ? hh : (__bf16)(f - (float)hh);
    }
    *(uint4*)(cbB + (size_t)id * 8) = p.u;

    if (blockIdx.x == 0) {
        const float4* row = (const float4*)(cb + (size_t)tid * 128);
        float a0 = 0.f, a1 = 0.f, a2 = 0.f, a3 = 0.f;
#pragma unroll 8
        for (int j = 0; j < 32; ++j) {
            float4 v = row[j];
            a0 = fmaf(v.x, v.x, a0);
            a1 = fmaf(v.y, v.y, a1);
            a2 = fmaf(v.z, v.z, a2);
            a3 = fmaf(v.w, v.w, a3);
        }
        csq[tid] = (a0 + a1) + (a2 + a3);
    }
}

// ---------------- Phase A: persistent-codebook MFMA scores + pair-merged top-2 ----------------
__global__ __launch_bounds__(512, 2) void knn_mfma(const float* __restrict__ x,
                                                   const __bf16* __restrict__ cbB,
                                                   const float* __restrict__ csq_g,
                                                   int* __restrict__ out,
                                                   int* __restrict__ cnt,
                                                   int* __restrict__ wl) {
    __shared__ __bf16 sB[65536];                 // 128 KB: ENTIRE split codebook
    __shared__ float sBF[2][4][2][32];           // [buf][pair][half][q] best
    __shared__ float sSF[2][4][2][32];           //                     second
    __shared__ int   sBI[2][4][2][32];           //                     best idx

    const int tid = threadIdx.x;
    const int wave = tid >> 6;                   // 0..7 (2 waves/SIMD)
    const int lane = tid & 63;
    const int rl = lane & 15;                    // n col within tile
    const int kg = lane >> 4;                    // k-group 0..3
    const int pair = wave >> 1;                  // 0..3
    const int half = wave & 1;                   // n-half: t in [half*8, half*8+8)

    // ---- one-time B fill: wave w copies 16 KB (16 x 1 KB, linear) ----
    {
        const char* gsrc = (const char*)cbB + wave * 16384 + lane * 16;
        char* ldst = (char*)sB + wave * 16384;
#pragma unroll
        for (int i = 0; i < 16; ++i)
            __builtin_amdgcn_global_load_lds((gu32*)(gsrc + i * 1024),
                                             (lu32*)(ldst + i * 1024), 16, 0, 0);
    }

    float cs[8];
#pragma unroll
    for (int t = 0; t < 8; ++t) cs[t] = csq_g[(half * 8 + t) * 16 + rl];

    // ---- 4 batches of 128 q (4 pairs x 32 q) ----
#pragma unroll 1
    for (int bt = 0; bt < 4; ++bt) {
        const int bb = bt & 1;
        const size_t q0 = (size_t)blockIdx.x * 512 + bt * 128 + pair * 32;

        // ---- A: load + split-convert this pair's 2 m-tiles (both waves same A) ----
        const float* xq = x + q0 * 128;
        bf16x8 ah[2][4], al[2][4];
#pragma unroll
        for (int m = 0; m < 2; ++m) {
#pragma unroll
            for (int kb = 0; kb < 4; ++kb) {
                const float* s = xq + (size_t)(m * 16 + rl) * 128 + kb * 32 + kg * 8;
                float4 f0 = *(const float4*)(s);
                float4 f1 = *(const float4*)(s + 4);
                float f[8] = {f0.x, f0.y, f0.z, f0.w, f1.x, f1.y, f1.z, f1.w};
                union { __bf16 h[8]; bf16x8 v; } ph, pl;
#pragma unroll
                for (int j = 0; j < 8; ++j) {
                    __bf16 hh = (__bf16)f[j];
                    ph.h[j] = hh;
                    pl.h[j] = (__bf16)(f[j] - (float)hh);
                }
                ah[m][kb] = ph.v;
                al[m][kb] = pl.v;
            }
        }

        floatx4 acc[2][8];
#pragma unroll
        for (int m = 0; m < 2; ++m)
#pragma unroll
            for (int t = 0; t < 8; ++t) acc[m][t] = (floatx4){0.f, 0.f, 0.f, 0.f};

        if (bt == 0) __syncthreads();            // B fill landed (vmcnt drain)

        // ---- K-loop: this wave's 8 n-tiles, pure LDS reads + MFMA ----
        // element offset = kb*16384 + (half*8+t)*1024 + part*512 + lane*8
#pragma unroll
        for (int kb = 0; kb < 4; ++kb) {
            const __bf16* sbase = sB + kb * 16384 + half * 8192 + lane * 8;
#pragma unroll
            for (int t = 0; t < 8; ++t) {
                bf16x8 bh = *(const bf16x8*)(sbase + t * 1024);
                bf16x8 bl = *(const bf16x8*)(sbase + t * 1024 + 512);
                acc[0][t] = MFMA16(ah[0][kb], bh, acc[0][t], 0, 0, 0);
                acc[1][t] = MFMA16(ah[1][kb], bh, acc[1][t], 0, 0, 0);
                acc[0][t] = MFMA16(al[0][kb], bh, acc[0][t], 0, 0, 0);
                acc[1][t] = MFMA16(al[1][kb], bh, acc[1][t], 0, 0, 0);
                acc[0][t] = MFMA16(ah[0][kb], bl, acc[0][t], 0, 0, 0);
                acc[1][t] = MFMA16(ah[1][kb], bl, acc[1][t], 0, 0, 0);
            }
        }

        // ---- epilogue: per-wave top-2 over this half's 128 codes ----
#pragma unroll
        for (int m = 0; m < 2; ++m) {
#pragma unroll
            for (int r = 0; r < 4; ++r) {
                float bf = __builtin_inff(), sf = __builtin_inff();
                int bi = 0;
#pragma unroll
                for (int t = 0; t < 8; ++t) {
                    const float sc = fmaf(-2.0f, acc[m][t][r], cs[t]);
                    const bool lt = sc < bf;
                    sf = lt ? bf : fminf(sf, sc);
                    bf = lt ? sc : bf;
                    bi = lt ? ((half * 8 + t) * 16 + rl) : bi;
                }
#pragma unroll
                for (int d = 1; d < 16; d <<= 1) {
                    const float obf = __shfl_xor(bf, d);
                    const int   obi = __shfl_xor(bi, d);
                    const float osf = __shfl_xor(sf, d);
                    const bool lt = obf < bf;
                    const float loser = lt ? bf : obf;       // larger best
                    sf = fminf(fminf(sf, osf), loser);
                    bf = lt ? obf : bf;
                    bi = lt ? obi : bi;
                }
                if (rl == 0) {
                    const int ql = m * 16 + kg * 4 + r;      // 0..31 within pair
                    sBF[bb][pair][half][ql] = bf;
                    sSF[bb][pair][half][ql] = sf;
                    sBI[bb][pair][half][ql] = bi;
                }
            }
        }

        __syncthreads();                         // epilogue writes visible

        // ---- merge: one owner wave per SIMD (waves 0,2,5,7), lanes 0..31 ----
        if (half == ((pair >> 1) & 1) && lane < 32) {
            const float b0 = sBF[bb][pair][0][lane];
            const float b1 = sBF[bb][pair][1][lane];
            const float s0 = sSF[bb][pair][0][lane];
            const float s1 = sSF[bb][pair][1][lane];
            const int   i0 = sBI[bb][pair][0][lane];
            const int   i1 = sBI[bb][pair][1][lane];
            const bool w0 = b0 < b1;
            const float B = w0 ? b0 : b1;
            const float S = fminf(w0 ? s0 : s1, w0 ? b1 : b0);
            out[q0 + lane] = w0 ? i0 : i1;
            if (S - B < T_FLAG) {                // gap small (or tie) -> exact pass
                int idx = atomicAdd(cnt, 1);
                if (idx < WL_CAP) wl[idx] = (int)(q0 + lane);
            }
        }
    }
}

// ---------------- Phase B: exact fp32 rescan, block-per-query ----------------
__global__ __launch_bounds__(256) void knn_refine(const float* __restrict__ x,
                                                  const float* __restrict__ cb,
                                                  const float* __restrict__ csq_g,
                                                  const int* __restrict__ wl,
                                                  const int* __restrict__ cnt,
                                                  int* __restrict__ out) {
    __shared__ unsigned long long sP[4];
    const int tid = threadIdx.x;           // == code index k
    const int lane = tid & 63;
    const int wave = tid >> 6;

    int n = *cnt;
    if (n > WL_CAP) n = WL_CAP;
    const float mycsq = csq_g[tid];
    const float4* cr = (const float4*)(cb + (size_t)tid * 128);

    for (int i = blockIdx.x; i < n; i += gridDim.x) {
        const int q = wl[i];
        const float4* qr = (const float4*)(x + (size_t)q * 128);
        float a0 = 0.f, a1 = 0.f, a2 = 0.f, a3 = 0.f;
#pragma unroll 8
        for (int c4 = 0; c4 < 32; ++c4) {
            float4 qv = qr[c4];            // broadcast (same addr all lanes)
            float4 cv = cr[c4];
            a0 = fmaf(qv.x, cv.x, a0);
            a1 = fmaf(qv.y, cv.y, a1);
            a2 = fmaf(qv.z, cv.z, a2);
            a3 = fmaf(qv.w, cv.w, a3);
        }
        float dot = (a0 + a1) + (a2 + a3);
        float score = fmaf(-2.0f, dot, mycsq);
        unsigned long long key =
            ((unsigned long long)fmap(score) << 32) | (unsigned)tid;
#pragma unroll
        for (int d = 1; d < 64; d <<= 1) {
            unsigned long long o = __shfl_xor(key, d);
            key = o < key ? o : key;
        }
        if (lane == 0) sP[wave] = key;
        __syncthreads();
        if (tid == 0) {
            unsigned long long b = sP[0];
            unsigned long long o;
            o = sP[1]; b = o < b ? o : b;
            o = sP[2]; b = o < b ? o : b;
            o = sP[3]; b = o < b ? o : b;
            out[q] = (int)(unsigned)(b & 0xFFFFFFFFull);
        }
        __syncthreads();
    }
}

extern "C" void kernel_launch(void* const* d_in, const int* in_sizes, int n_in,
                              void* d_out, int out_size, void* d_ws, size_t ws_size,
                              hipStream_t stream) {
    const float* x = (const float*)d_in[0];
    const float* cb = (const float*)d_in[1];
    int* out = (int*)d_out;

    char* ws = (char*)d_ws;
    int* cnt = (int*)(ws + CNT_OFF);
    float* csq = (float*)(ws + CSQ_OFF);
    __bf16* cbB = (__bf16*)(ws + CBB_OFF);
    int* wl = (int*)(ws + WL_OFF);

    const int M = in_sizes[0] / 128;     // 131072

    knn_prep<<<32, 256, 0, stream>>>(cb, cbB, csq, cnt);
    knn_mfma<<<M / 512, 512, 0, stream>>>(x, cbB, csq, out, cnt, wl);
    knn_refine<<<240, 256, 0, stream>>>(x, cb, csq, wl, cnt, out);
}